// Round 6
// baseline (89.352 us; speedup 1.0000x reference)
//
#include <hip/hip_runtime.h>
#include <hip/hip_bf16.h>

// B=8, N=256, D=128, H=256, K=128
// out[b,i,j,k] = exp(-(v - means[k])^2 * |temps[k]|)
//   v    = mul * x[b,i,j] + bias
//   mul  = (sum_h relu(hi[b,i,h]+hj[b,j,h]+b1[h]) * W2[h,0] + b2[0]) * 0.0625
//   bias = (                 "                    * W2[h,1] + b2[1]) * 0.0625

#define NB 8
#define NN 256
#define ND 128
#define NH 256
#define NK 128

typedef float f32x2 __attribute__((ext_vector_type(2)));

// ---------------- Kernel A: hi[bi][h] and hjbT[b][h][j] = hj + b1 ----------------
__global__ __launch_bounds__(256) void precompute_hij(
    const float* __restrict__ atom, const float* __restrict__ W1,
    const float* __restrict__ b1,
    float* __restrict__ hi, float* __restrict__ hjbT) {
  const int h = threadIdx.x;          // 0..255
  const int base = blockIdx.x * 8;    // bn base (multiple of 8 -> same b)
  const int b  = base >> 8;
  const int j0 = base & 255;
  __shared__ float a[8][ND];
  for (int t = threadIdx.x; t < 8 * ND; t += 256) {
    a[t >> 7][t & 127] = atom[(size_t)base * ND + t];
  }
  __syncthreads();
  float acc0[8], acc1[8];
  const float bv = b1[h];
#pragma unroll
  for (int r = 0; r < 8; ++r) { acc0[r] = 0.f; acc1[r] = bv; }
  for (int d = 0; d < ND; ++d) {
    const float w0 = W1[d * NH + h];
    const float w1 = W1[(ND + d) * NH + h];
#pragma unroll
    for (int r = 0; r < 8; ++r) {
      acc0[r] = fmaf(a[r][d], w0, acc0[r]);
      acc1[r] = fmaf(a[r][d], w1, acc1[r]);
    }
  }
#pragma unroll
  for (int r = 0; r < 8; ++r) {
    hi[(size_t)(base + r) * NH + h] = acc0[r];
    hjbT[((size_t)b * NH + h) * NN + (j0 + r)] = acc1[r];
  }
}

// ---------------- Kernel B: barrier-free, LDS-free ----------------
// grid = B*N/2 blocks (1024); b = blockIdx&7 (XCD-L2 locality).
// 256 threads = 4 waves; wave w: row = i0 + (w>>1), j-half = w&1.
// Lane l: dot for j = j0+2l, j0+2l+1 over all 256 h (hi/W2 scalar-uniform).
// Phase 2: readlane-broadcast v[j]; lane l covers k = 2l, 2l+1.
__global__ __launch_bounds__(256) void edge_rbf(
    const float* __restrict__ x,
    const float* __restrict__ hi, const float* __restrict__ hjbT,
    const float* __restrict__ W2, const float* __restrict__ b2,
    const float* __restrict__ means, const float* __restrict__ temps,
    float* __restrict__ out) {
  const int b    = blockIdx.x & 7;
  const int i0   = (blockIdx.x >> 3) * 2;
  const int wv   = __builtin_amdgcn_readfirstlane((int)(threadIdx.x >> 6)); // 0..3, SGPR
  const int lane = threadIdx.x & 63;
  const int row  = i0 + (wv >> 1);
  const int j0   = (wv & 1) * 128;
  const int bi   = b * NN + row;

  // ---- Phase 1: full-H dot, lanes over j (2 j per lane) ----
  const float* __restrict__ hjcol = hjbT + (size_t)b * NH * NN + j0 + 2 * lane;
  const float* __restrict__ hirow = hi + (size_t)bi * NH;   // uniform base (SGPR)

  float s0a = 0.f, s1a = 0.f, s0b = 0.f, s1b = 0.f;
#pragma unroll 8
  for (int h = 0; h < NH; ++h) {
    const f32x2 hj = *reinterpret_cast<const f32x2*>(hjcol + (size_t)h * NN);
    const float hih = hirow[h];        // wave-uniform -> s_load
    const float w0  = W2[2 * h];       // wave-uniform
    const float w1  = W2[2 * h + 1];
    const float a0 = fmaxf(hih + hj.x, 0.f);
    const float a1 = fmaxf(hih + hj.y, 0.f);
    s0a = fmaf(a0, w0, s0a); s1a = fmaf(a0, w1, s1a);
    s0b = fmaf(a1, w0, s0b); s1b = fmaf(a1, w1, s1b);
  }

  const float scale = 0.0625f;  // 1/sqrt(2*128)
  const float b20 = b2[0], b21 = b2[1];
  const f32x2 xv = *reinterpret_cast<const f32x2*>(x + (size_t)bi * NN + j0 + 2 * lane);
  const float va = fmaf((s0a + b20) * scale, xv.x, (s1a + b21) * scale);
  const float vb = fmaf((s0b + b20) * scale, xv.y, (s1b + b21) * scale);

  // ---- Phase 2: RBF + store; lane l covers k = 2l, 2l+1 ----
  const float LOG2E = 1.44269504088896340736f;
  const f32x2 mk = *reinterpret_cast<const f32x2*>(means + 2 * lane);
  f32x2 tk = *reinterpret_cast<const f32x2*>(temps + 2 * lane);
  const float t0 = -fabsf(tk.x) * LOG2E;
  const float t1 = -fabsf(tk.y) * LOG2E;

  float* __restrict__ obase = out + ((size_t)bi * NN + j0) * NK + 2 * lane;
  const int va_i = __float_as_int(va);
  const int vb_i = __float_as_int(vb);

#pragma unroll 8
  for (int c = 0; c < 64; ++c) {
    const float vj0 = __int_as_float(__builtin_amdgcn_readlane(va_i, c)); // j = j0+2c
    const float vj1 = __int_as_float(__builtin_amdgcn_readlane(vb_i, c)); // j = j0+2c+1
    const float d00 = vj0 - mk.x, d01 = vj0 - mk.y;
    const float d10 = vj1 - mk.x, d11 = vj1 - mk.y;
    f32x2 e0, e1;
    e0.x = __builtin_amdgcn_exp2f(d00 * d00 * t0);
    e0.y = __builtin_amdgcn_exp2f(d01 * d01 * t1);
    e1.x = __builtin_amdgcn_exp2f(d10 * d10 * t0);
    e1.y = __builtin_amdgcn_exp2f(d11 * d11 * t1);
    *reinterpret_cast<f32x2*>(obase + (size_t)(2 * c) * NK)     = e0;
    *reinterpret_cast<f32x2*>(obase + (size_t)(2 * c + 1) * NK) = e1;
  }
}

extern "C" void kernel_launch(void* const* d_in, const int* in_sizes, int n_in,
                              void* d_out, int out_size, void* d_ws, size_t ws_size,
                              hipStream_t stream) {
  const float* x     = (const float*)d_in[0];
  const float* atom  = (const float*)d_in[1];
  const float* W1    = (const float*)d_in[2];
  const float* b1    = (const float*)d_in[3];
  const float* W2    = (const float*)d_in[4];
  const float* b2    = (const float*)d_in[5];
  const float* means = (const float*)d_in[6];
  const float* temps = (const float*)d_in[7];
  float* out = (float*)d_out;

  float* hi   = (float*)d_ws;                        // 2 MB: [B*N][H]
  float* hjbT = hi + (size_t)NB * NN * NH;           // 2 MB: [B][H][N]

  precompute_hij<<<NB * NN / 8, 256, 0, stream>>>(atom, W1, b1, hi, hjbT);
  edge_rbf<<<NB * NN / 2, 256, 0, stream>>>(x, hi, hjbT, W2, b2, means, temps, out);
}

// Round 7
// 84.933 us; speedup vs baseline: 1.0520x; 1.0520x over previous
//
#include <hip/hip_runtime.h>
#include <hip/hip_bf16.h>

// B=8, N=256, D=128, H=256, K=128
// out[b,i,j,k] = exp(-(v - means[k])^2 * |temps[k]|)
//   v    = mul * x[b,i,j] + bias
//   mul  = (sum_h relu(hi[b,i,h]+hj[b,j,h]+b1[h]) * W2[h,0] + b2[0]) * 0.0625
//   bias = (                 "                    * W2[h,1] + b2[1]) * 0.0625

#define NB 8
#define NN 256
#define ND 128
#define NH 256
#define NK 128
#define GI 2   // i-rows per block in compute_v

typedef float f32x4 __attribute__((ext_vector_type(4)));

// ---------------- Kernel A: hi[bi][h] and hjbT[b][h][j] = hj + b1 ----------------
__global__ __launch_bounds__(256) void precompute_hij(
    const float* __restrict__ atom, const float* __restrict__ W1,
    const float* __restrict__ b1,
    float* __restrict__ hi, float* __restrict__ hjbT) {
  const int h = threadIdx.x;          // 0..255
  const int base = blockIdx.x * 8;    // bn base (multiple of 8 -> same b)
  const int b  = base >> 8;
  const int j0 = base & 255;
  __shared__ float a[8][ND];
  for (int t = threadIdx.x; t < 8 * ND; t += 256) {
    a[t >> 7][t & 127] = atom[(size_t)base * ND + t];
  }
  __syncthreads();
  float acc0[8], acc1[8];
  const float bv = b1[h];
#pragma unroll
  for (int r = 0; r < 8; ++r) { acc0[r] = 0.f; acc1[r] = bv; }
  for (int d = 0; d < ND; ++d) {
    const float w0 = W1[d * NH + h];
    const float w1 = W1[(ND + d) * NH + h];
#pragma unroll
    for (int r = 0; r < 8; ++r) {
      acc0[r] = fmaf(a[r][d], w0, acc0[r]);
      acc1[r] = fmaf(a[r][d], w1, acc1[r]);
    }
  }
#pragma unroll
  for (int r = 0; r < 8; ++r) {
    hi[(size_t)(base + r) * NH + h] = acc0[r];
    hjbT[((size_t)b * NH + h) * NN + (j0 + r)] = acc1[r];
  }
}

// ---------------- Kernel B: v[b,i,j] (R5 phase-1 structure, 2 MB output) ----------------
// grid = B*N/GI blocks; b = blockIdx&7 (XCD-L2 locality), 256 threads = 4 waves.
// Wave w reduces h in [64w,64w+64) for GI rows; lanes over j (float4).
__global__ __launch_bounds__(256) void compute_v(
    const float* __restrict__ x,
    const float* __restrict__ hi, const float* __restrict__ hjbT,
    const float* __restrict__ W2, const float* __restrict__ b2,
    float* __restrict__ v) {
  const int b    = blockIdx.x & 7;
  const int i0   = (blockIdx.x >> 3) * GI;
  const int lane = threadIdx.x & 63;
  const int wave = threadIdx.x >> 6;

  __shared__ float part0[4][GI][NN];   // 8 KB
  __shared__ float part1[4][GI][NN];   // 8 KB

  const float* __restrict__ hjrow  = hjbT + ((size_t)b * NH + wave * 64) * NN;
  const float* __restrict__ w2row  = W2 + wave * 128;
  const float* __restrict__ hibase = hi + ((size_t)(b * NN + i0)) * NH + wave * 64;

  float acc0[GI][4], acc1[GI][4];
#pragma unroll
  for (int r = 0; r < GI; ++r)
#pragma unroll
    for (int q = 0; q < 4; ++q) { acc0[r][q] = 0.f; acc1[r][q] = 0.f; }

#pragma unroll 8
  for (int hh = 0; hh < 64; ++hh) {
    const float4 hj4 = *reinterpret_cast<const float4*>(hjrow + (size_t)hh * NN + 4 * lane);
    const float w0 = w2row[2 * hh];
    const float w1 = w2row[2 * hh + 1];
#pragma unroll
    for (int r = 0; r < GI; ++r) {
      const float hih = hibase[(size_t)r * NH + hh];  // wave-uniform
      const float a0 = fmaxf(hih + hj4.x, 0.f);
      const float a1 = fmaxf(hih + hj4.y, 0.f);
      const float a2 = fmaxf(hih + hj4.z, 0.f);
      const float a3 = fmaxf(hih + hj4.w, 0.f);
      acc0[r][0] = fmaf(a0, w0, acc0[r][0]); acc1[r][0] = fmaf(a0, w1, acc1[r][0]);
      acc0[r][1] = fmaf(a1, w0, acc0[r][1]); acc1[r][1] = fmaf(a1, w1, acc1[r][1]);
      acc0[r][2] = fmaf(a2, w0, acc0[r][2]); acc1[r][2] = fmaf(a2, w1, acc1[r][2]);
      acc0[r][3] = fmaf(a3, w0, acc0[r][3]); acc1[r][3] = fmaf(a3, w1, acc1[r][3]);
    }
  }
#pragma unroll
  for (int r = 0; r < GI; ++r) {
    *reinterpret_cast<float4*>(&part0[wave][r][4 * lane]) =
        make_float4(acc0[r][0], acc0[r][1], acc0[r][2], acc0[r][3]);
    *reinterpret_cast<float4*>(&part1[wave][r][4 * lane]) =
        make_float4(acc1[r][0], acc1[r][1], acc1[r][2], acc1[r][3]);
  }
  __syncthreads();

  {
    const int t = threadIdx.x;
    const float scale = 0.0625f;
    const float b20 = b2[0], b21 = b2[1];
#pragma unroll
    for (int r = 0; r < GI; ++r) {
      const float s0 = part0[0][r][t] + part0[1][r][t] + part0[2][r][t] + part0[3][r][t];
      const float s1 = part1[0][r][t] + part1[1][r][t] + part1[2][r][t] + part1[3][r][t];
      const float mul  = (s0 + b20) * scale;
      const float bias = (s1 + b21) * scale;
      const size_t bij = (size_t)(b * NN + i0 + r) * NN + t;
      v[bij] = fmaf(mul, x[bij], bias);
    }
  }
}

// ---------------- Kernel C: pure streaming RBF ----------------
// 2048 blocks x 256 threads; thread -> (k-quad fixed, bij strided).
// Per s-iter: broadcast v load + 12 VALU + 4 exp2 + float4 store.
__global__ __launch_bounds__(256) void rbf_store(
    const float* __restrict__ v,
    const float* __restrict__ means, const float* __restrict__ temps,
    float* __restrict__ out) {
  const int idx = blockIdx.x * 256 + threadIdx.x;   // 0..524287
  const int k0  = (idx & 31) * 4;                   // constant per thread

  const float LOG2E = 1.44269504088896340736f;
  const float4 mv = *reinterpret_cast<const float4*>(means + k0);
  float4 tv = *reinterpret_cast<const float4*>(temps + k0);
  const float t0 = -fabsf(tv.x) * LOG2E;
  const float t1 = -fabsf(tv.y) * LOG2E;
  const float t2 = -fabsf(tv.z) * LOG2E;
  const float t3 = -fabsf(tv.w) * LOG2E;

  const float* __restrict__ vp = v + (idx >> 5);    // +16384 per s
  float* __restrict__ op = out + (size_t)idx * 4;   // +2097152 floats per s

#pragma unroll 4
  for (int s = 0; s < 32; ++s) {
    const float vj = vp[s * 16384];
    const float d0 = vj - mv.x;
    const float d1 = vj - mv.y;
    const float d2 = vj - mv.z;
    const float d3 = vj - mv.w;
    f32x4 e;
    e.x = __builtin_amdgcn_exp2f(d0 * d0 * t0);
    e.y = __builtin_amdgcn_exp2f(d1 * d1 * t1);
    e.z = __builtin_amdgcn_exp2f(d2 * d2 * t2);
    e.w = __builtin_amdgcn_exp2f(d3 * d3 * t3);
    *reinterpret_cast<f32x4*>(op + (size_t)s * 2097152) = e;
  }
}

extern "C" void kernel_launch(void* const* d_in, const int* in_sizes, int n_in,
                              void* d_out, int out_size, void* d_ws, size_t ws_size,
                              hipStream_t stream) {
  const float* x     = (const float*)d_in[0];
  const float* atom  = (const float*)d_in[1];
  const float* W1    = (const float*)d_in[2];
  const float* b1    = (const float*)d_in[3];
  const float* W2    = (const float*)d_in[4];
  const float* b2    = (const float*)d_in[5];
  const float* means = (const float*)d_in[6];
  const float* temps = (const float*)d_in[7];
  float* out = (float*)d_out;

  float* hi   = (float*)d_ws;                        // 2 MB: [B*N][H]
  float* hjbT = hi + (size_t)NB * NN * NH;           // 2 MB: [B][H][N]
  float* v    = hjbT + (size_t)NB * NH * NN;         // 2 MB: [B*N*N]

  precompute_hij<<<NB * NN / 8, 256, 0, stream>>>(atom, W1, b1, hi, hjbT);
  compute_v<<<NB * NN / GI, 256, 0, stream>>>(x, hi, hjbT, W2, b2, v);
  rbf_store<<<2048, 256, 0, stream>>>(v, means, temps, out);
}

// Round 8
// 77.247 us; speedup vs baseline: 1.1567x; 1.0995x over previous
//
#include <hip/hip_runtime.h>
#include <hip/hip_bf16.h>

// B=8, N=256, D=128, H=256, K=128
// out[b,i,j,k] = exp(-(v - means[k])^2 * |temps[k]|)
//   v    = mul * x[b,i,j] + bias
//   mul  = (sum_h relu(hi[b,i,h]+hj[b,j,h]+b1[h]) * W2[h,0] + b2[0]) * 0.0625
//   bias = (                 "                    * W2[h,1] + b2[1]) * 0.0625

#define NB 8
#define NN 256
#define ND 128
#define NH 256
#define NK 128

typedef float f32x4 __attribute__((ext_vector_type(4)));

// ---------------- Kernel A: hi[bi][h] and hjbT[b][h][j] = hj + b1 ----------------
__global__ __launch_bounds__(256) void precompute_hij(
    const float* __restrict__ atom, const float* __restrict__ W1,
    const float* __restrict__ b1,
    float* __restrict__ hi, float* __restrict__ hjbT) {
  const int h = threadIdx.x;          // 0..255
  const int base = blockIdx.x * 8;    // bn base (multiple of 8 -> same b)
  const int b  = base >> 8;
  const int j0 = base & 255;
  __shared__ float a[8][ND];
  for (int t = threadIdx.x; t < 8 * ND; t += 256) {
    a[t >> 7][t & 127] = atom[(size_t)base * ND + t];
  }
  __syncthreads();
  float acc0[8], acc1[8];
  const float bv = b1[h];
#pragma unroll
  for (int r = 0; r < 8; ++r) { acc0[r] = 0.f; acc1[r] = bv; }
  for (int d = 0; d < ND; ++d) {
    const float w0 = W1[d * NH + h];
    const float w1 = W1[(ND + d) * NH + h];
#pragma unroll
    for (int r = 0; r < 8; ++r) {
      acc0[r] = fmaf(a[r][d], w0, acc0[r]);
      acc1[r] = fmaf(a[r][d], w1, acc1[r]);
    }
  }
#pragma unroll
  for (int r = 0; r < 8; ++r) {
    hi[(size_t)(base + r) * NH + h] = acc0[r];
    hjbT[((size_t)b * NH + h) * NN + (j0 + r)] = acc1[r];
  }
}

// ---------------- Fused kernel: one (b,i) row per 1024-thread block ----------------
// grid 2048; only 2 blocks/CU resident (thread cap) -> 4 generations pipeline:
// gen g's phase-1 compute overlaps gen g-1's phase-2 stores.
// Phase 1: wave w (of 16) reduces h in [16w,16w+16); lanes over j (float4).
// Reduce: threads 0..255 sum 16 partials, v = mul*x + bias -> vsh.
// Phase 2: wave w stores j in [16w,16w+16); lane: k0=4(l&31), jhalf=l>>5.
__global__ __launch_bounds__(1024, 8) void edge_rbf(
    const float* __restrict__ x,
    const float* __restrict__ hi, const float* __restrict__ hjbT,
    const float* __restrict__ W2, const float* __restrict__ b2,
    const float* __restrict__ means, const float* __restrict__ temps,
    float* __restrict__ out) {
  const int b    = blockIdx.x & 7;       // XCD-L2 locality
  const int i    = blockIdx.x >> 3;
  const int bi   = b * NN + i;
  const int tid  = threadIdx.x;
  const int lane = tid & 63;
  const int wave = tid >> 6;             // 0..15

  __shared__ float part0[16][NN];        // 16 KB
  __shared__ float part1[16][NN];        // 16 KB
  __shared__ float vsh[NN];              // 1 KB

  // ---- Phase 1: h in [16w, 16w+16), 4 j per lane ----
  const float* __restrict__ hjrow = hjbT + ((size_t)b * NH + wave * 16) * NN + 4 * lane;
  const float* __restrict__ hirow = hi + (size_t)bi * NH + wave * 16;
  const float* __restrict__ w2row = W2 + wave * 32;

  float acc0[4] = {0.f, 0.f, 0.f, 0.f};
  float acc1[4] = {0.f, 0.f, 0.f, 0.f};
#pragma unroll 4
  for (int hh = 0; hh < 16; ++hh) {
    const float4 hj4 = *reinterpret_cast<const float4*>(hjrow + (size_t)hh * NN);
    const float hih = hirow[hh];        // wave-uniform
    const float w0  = w2row[2 * hh];
    const float w1  = w2row[2 * hh + 1];
    const float a0 = fmaxf(hih + hj4.x, 0.f);
    const float a1 = fmaxf(hih + hj4.y, 0.f);
    const float a2 = fmaxf(hih + hj4.z, 0.f);
    const float a3 = fmaxf(hih + hj4.w, 0.f);
    acc0[0] = fmaf(a0, w0, acc0[0]); acc1[0] = fmaf(a0, w1, acc1[0]);
    acc0[1] = fmaf(a1, w0, acc0[1]); acc1[1] = fmaf(a1, w1, acc1[1]);
    acc0[2] = fmaf(a2, w0, acc0[2]); acc1[2] = fmaf(a2, w1, acc1[2]);
    acc0[3] = fmaf(a3, w0, acc0[3]); acc1[3] = fmaf(a3, w1, acc1[3]);
  }
  *reinterpret_cast<float4*>(&part0[wave][4 * lane]) =
      make_float4(acc0[0], acc0[1], acc0[2], acc0[3]);
  *reinterpret_cast<float4*>(&part1[wave][4 * lane]) =
      make_float4(acc1[0], acc1[1], acc1[2], acc1[3]);
  __syncthreads();

  // ---- Reduce (threads 0..255) ----
  if (tid < NN) {
    float s0 = 0.f, s1 = 0.f;
#pragma unroll
    for (int w = 0; w < 16; ++w) { s0 += part0[w][tid]; s1 += part1[w][tid]; }
    const float scale = 0.0625f;  // 1/sqrt(2*128)
    const float mul  = (s0 + b2[0]) * scale;
    const float bias = (s1 + b2[1]) * scale;
    vsh[tid] = fmaf(mul, x[(size_t)bi * NN + tid], bias);
  }
  __syncthreads();

  // ---- Phase 2: RBF + store, wave w covers j in [16w,16w+16) ----
  const int k0 = (lane & 31) * 4;
  const int jhalf = lane >> 5;
  const float LOG2E = 1.44269504088896340736f;
  const float4 mv = *reinterpret_cast<const float4*>(means + k0);
  const float4 tl = *reinterpret_cast<const float4*>(temps + k0);
  const float t0 = -fabsf(tl.x) * LOG2E;
  const float t1 = -fabsf(tl.y) * LOG2E;
  const float t2 = -fabsf(tl.z) * LOG2E;
  const float t3 = -fabsf(tl.w) * LOG2E;

  float* __restrict__ orow = out + ((size_t)bi * NN + wave * 16) * NK;
#pragma unroll 4
  for (int c = 0; c < 8; ++c) {
    const int j = 2 * c + jhalf;
    const float vj = vsh[wave * 16 + j];
    const float d0 = vj - mv.x;
    const float d1 = vj - mv.y;
    const float d2 = vj - mv.z;
    const float d3 = vj - mv.w;
    f32x4 e;
    e.x = __builtin_amdgcn_exp2f(d0 * d0 * t0);
    e.y = __builtin_amdgcn_exp2f(d1 * d1 * t1);
    e.z = __builtin_amdgcn_exp2f(d2 * d2 * t2);
    e.w = __builtin_amdgcn_exp2f(d3 * d3 * t3);
    *reinterpret_cast<f32x4*>(orow + (size_t)j * NK + k0) = e;
  }
}

extern "C" void kernel_launch(void* const* d_in, const int* in_sizes, int n_in,
                              void* d_out, int out_size, void* d_ws, size_t ws_size,
                              hipStream_t stream) {
  const float* x     = (const float*)d_in[0];
  const float* atom  = (const float*)d_in[1];
  const float* W1    = (const float*)d_in[2];
  const float* b1    = (const float*)d_in[3];
  const float* W2    = (const float*)d_in[4];
  const float* b2    = (const float*)d_in[5];
  const float* means = (const float*)d_in[6];
  const float* temps = (const float*)d_in[7];
  float* out = (float*)d_out;

  float* hi   = (float*)d_ws;                        // 2 MB: [B*N][H]
  float* hjbT = hi + (size_t)NB * NN * NH;           // 2 MB: [B][H][N]

  precompute_hij<<<NB * NN / 8, 256, 0, stream>>>(atom, W1, b1, hi, hjbT);
  edge_rbf<<<NB * NN, 1024, 0, stream>>>(x, hi, hjbT, W2, b2, means, temps, out);
}